// Round 1
// baseline (30.158 us; speedup 1.0000x reference)
//
#include <hip/hip_runtime.h>

#define BEV_H 150
#define BEV_W 150
#define DD    4
#define NCAM  6
#define CC    128
#define FH    48
#define FW    88
#define IMG_H 480.0f
#define IMG_W 800.0f

#define NPTS (NCAM * DD)   // 24 projected points per BEV cell

__global__ __launch_bounds__(CC) void bev_sample_kernel(
    const float* __restrict__ feat,   // (NCAM, FH, FW, C)
    const float* __restrict__ I_,     // (NCAM, 3, 3)
    const float* __restrict__ E_,     // (NCAM, 4, 4)
    const float* __restrict__ grid,   // (D, 3, BEV_H, BEV_W)
    float* __restrict__ out)          // (Q, C)
{
    const int q = blockIdx.x;
    const int h = q / BEV_W;
    const int w = q % BEV_W;
    const int t = threadIdx.x;

    __shared__ float s_l2i[NCAM][12];      // 3x4 cam matrices
    __shared__ int   s_idx[NPTS][4];       // 4 corner flat offsets (pre-scaled by C)
    __shared__ float s_w[NPTS][4];         // 4 corner weights (mask & validity folded in)
    __shared__ float s_mask[NPTS];

    // --- build l2i = I @ E[:3,:]  (72 elements, one per thread) ---
    if (t < NCAM * 12) {
        const int n = t / 12;
        const int r = t % 12;
        const int i = r / 4, j = r % 4;
        float acc = 0.f;
        #pragma unroll
        for (int k = 0; k < 3; ++k)
            acc += I_[n * 9 + i * 3 + k] * E_[n * 16 + k * 4 + j];
        s_l2i[n][r] = acc;
    }
    __syncthreads();

    // --- project 24 points, one per thread ---
    if (t < NPTS) {
        const int n = t / DD;
        const int d = t % DD;
        const float gx = grid[((d * 3 + 0) * BEV_H + h) * BEV_W + w];
        const float gy = grid[((d * 3 + 1) * BEV_H + h) * BEV_W + w];
        const float gz = grid[((d * 3 + 2) * BEV_H + h) * BEV_W + w];
        // scale = PC[3:6]-PC[0:3] = (102.4, 102.4, 8.0); off = (-51.2,-51.2,-5.0)
        const float x = gx * 102.4f - 51.2f;
        const float y = gy * 102.4f - 51.2f;
        const float z = gz * 8.0f   - 5.0f;
        const float* M = s_l2i[n];
        const float p0 = M[0] * x + M[1] * y + M[2]  * z + M[3];
        const float p1 = M[4] * x + M[5] * y + M[6]  * z + M[7];
        const float p2 = M[8] * x + M[9] * y + M[10] * z + M[11];

        const float eps = 1e-5f;
        const float zc = fmaxf(p2, eps);
        const float u = (p0 / zc) / IMG_W;
        const float v = (p1 / zc) / IMG_H;
        const bool m = (p2 > eps) && (u > 0.f) && (u < 1.f) && (v > 0.f) && (v < 1.f);

        const float px = u * (float)FW - 0.5f;
        const float py = v * (float)FH - 0.5f;
        const float fx0 = floorf(px), fy0 = floorf(py);
        const int x0 = (int)fx0, y0 = (int)fy0;
        const int x1 = x0 + 1,   y1 = y0 + 1;
        const float wx1 = px - fx0, wy1 = py - fy0;
        const float wx0 = 1.f - wx1, wy0 = 1.f - wy1;

        const float mm = m ? 1.f : 0.f;
        const bool vx0 = (x0 >= 0) && (x0 < FW);
        const bool vx1 = (x1 >= 0) && (x1 < FW);
        const bool vy0 = (y0 >= 0) && (y0 < FH);
        const bool vy1 = (y1 >= 0) && (y1 < FH);
        const int cx0 = min(max(x0, 0), FW - 1), cx1 = min(max(x1, 0), FW - 1);
        const int cy0 = min(max(y0, 0), FH - 1), cy1 = min(max(y1, 0), FH - 1);
        const int base = n * FH * FW;

        s_idx[t][0] = (base + cy0 * FW + cx0) * CC;
        s_idx[t][1] = (base + cy0 * FW + cx1) * CC;
        s_idx[t][2] = (base + cy1 * FW + cx0) * CC;
        s_idx[t][3] = (base + cy1 * FW + cx1) * CC;
        s_w[t][0] = mm * wx0 * wy0 * ((vx0 && vy0) ? 1.f : 0.f);
        s_w[t][1] = mm * wx1 * wy0 * ((vx1 && vy0) ? 1.f : 0.f);
        s_w[t][2] = mm * wx0 * wy1 * ((vx0 && vy1) ? 1.f : 0.f);
        s_w[t][3] = mm * wx1 * wy1 * ((vx1 && vy1) ? 1.f : 0.f);
        s_mask[t] = mm;
    }
    __syncthreads();

    // --- count of valid points (uniform across block; cheap redundant sum) ---
    float cnt = 0.f;
    #pragma unroll
    for (int e = 0; e < NPTS; ++e) cnt += s_mask[e];
    cnt = fmaxf(cnt, 1.f);

    // --- per-channel accumulation: lane t handles channel t ---
    float acc = 0.f;
    for (int e = 0; e < NPTS; ++e) {
        if (s_mask[e] == 0.f) continue;   // block-uniform branch
        acc += s_w[e][0] * feat[s_idx[e][0] + t];
        acc += s_w[e][1] * feat[s_idx[e][1] + t];
        acc += s_w[e][2] * feat[s_idx[e][2] + t];
        acc += s_w[e][3] * feat[s_idx[e][3] + t];
    }
    out[q * CC + t] = acc / cnt;
}

extern "C" void kernel_launch(void* const* d_in, const int* in_sizes, int n_in,
                              void* d_out, int out_size, void* d_ws, size_t ws_size,
                              hipStream_t stream) {
    const float* feat = (const float*)d_in[0];
    const float* I_   = (const float*)d_in[1];
    const float* E_   = (const float*)d_in[2];
    const float* grid = (const float*)d_in[3];
    float* out        = (float*)d_out;

    bev_sample_kernel<<<BEV_H * BEV_W, CC, 0, stream>>>(feat, I_, E_, grid, out);
}

// Round 2
// 27.434 us; speedup vs baseline: 1.0993x; 1.0993x over previous
//
#include <hip/hip_runtime.h>

#define BEV_H 150
#define BEV_W 150
#define DD    4
#define NCAM  6
#define CC    128
#define FH    48
#define FW    88
#define IMG_H 480.0f
#define IMG_W 800.0f

#define NPTS (NCAM * DD)   // 24 projected points per BEV cell
#define WPB  4             // waves (= BEV cells) per block

__global__ __launch_bounds__(WPB * 64) void bev_sample_kernel(
    const float* __restrict__ feat,   // (NCAM, FH, FW, C)
    const float* __restrict__ I_,     // (NCAM, 3, 3)
    const float* __restrict__ E_,     // (NCAM, 4, 4)
    const float* __restrict__ grid,   // (D, 3, BEV_H, BEV_W)
    float* __restrict__ out)          // (Q, C)
{
    const int lane = threadIdx.x & 63;
    const int wv   = threadIdx.x >> 6;
    const int q    = blockIdx.x * WPB + wv;   // 22500 = 5625 * 4, exact
    const int h    = q / BEV_W;
    const int w    = q % BEV_W;

    // per-point state (defined on lanes 0..23 only; others never read)
    int   i0 = 0, i1 = 0, i2 = 0, i3 = 0;
    float w0 = 0.f, w1 = 0.f, w2 = 0.f, w3 = 0.f;
    bool  m = false;

    if (lane < NPTS) {
        const int n = lane >> 2;   // camera
        const int d = lane & 3;    // depth

        // l2i = I[n] @ E[n][:3,:]  (3x4), fully in-register
        float M[12];
        #pragma unroll
        for (int i = 0; i < 3; ++i) {
            #pragma unroll
            for (int j = 0; j < 4; ++j) {
                float acc = 0.f;
                #pragma unroll
                for (int k = 0; k < 3; ++k)
                    acc += I_[n * 9 + i * 3 + k] * E_[n * 16 + k * 4 + j];
                M[i * 4 + j] = acc;
            }
        }

        const float gx = grid[((d * 3 + 0) * BEV_H + h) * BEV_W + w];
        const float gy = grid[((d * 3 + 1) * BEV_H + h) * BEV_W + w];
        const float gz = grid[((d * 3 + 2) * BEV_H + h) * BEV_W + w];
        // scale = (102.4, 102.4, 8.0); off = (-51.2, -51.2, -5.0)
        const float x = gx * 102.4f - 51.2f;
        const float y = gy * 102.4f - 51.2f;
        const float z = gz * 8.0f   - 5.0f;

        const float p0 = M[0] * x + M[1] * y + M[2]  * z + M[3];
        const float p1 = M[4] * x + M[5] * y + M[6]  * z + M[7];
        const float p2 = M[8] * x + M[9] * y + M[10] * z + M[11];

        const float eps = 1e-5f;
        const float zc = fmaxf(p2, eps);
        const float u = (p0 / zc) * (1.0f / IMG_W);
        const float v = (p1 / zc) * (1.0f / IMG_H);
        m = (p2 > eps) && (u > 0.f) && (u < 1.f) && (v > 0.f) && (v < 1.f);

        const float px = u * (float)FW - 0.5f;
        const float py = v * (float)FH - 0.5f;
        const float fx0 = floorf(px), fy0 = floorf(py);
        const int x0 = (int)fx0, y0 = (int)fy0;
        const int x1 = x0 + 1,   y1 = y0 + 1;
        const float wx1 = px - fx0, wy1 = py - fy0;
        const float wx0 = 1.f - wx1, wy0 = 1.f - wy1;

        const bool vx0 = (x0 >= 0) && (x0 < FW);
        const bool vx1 = (x1 >= 0) && (x1 < FW);
        const bool vy0 = (y0 >= 0) && (y0 < FH);
        const bool vy1 = (y1 >= 0) && (y1 < FH);
        const int cx0 = min(max(x0, 0), FW - 1), cx1 = min(max(x1, 0), FW - 1);
        const int cy0 = min(max(y0, 0), FH - 1), cy1 = min(max(y1, 0), FH - 1);
        const int base = n * FH * FW;

        i0 = (base + cy0 * FW + cx0) * CC;
        i1 = (base + cy0 * FW + cx1) * CC;
        i2 = (base + cy1 * FW + cx0) * CC;
        i3 = (base + cy1 * FW + cx1) * CC;
        // mask folded into weights (only reached when m; loop skips m==0)
        w0 = wx0 * wy0 * ((vx0 && vy0) ? 1.f : 0.f);
        w1 = wx1 * wy0 * ((vx1 && vy0) ? 1.f : 0.f);
        w2 = wx0 * wy1 * ((vx0 && vy1) ? 1.f : 0.f);
        w3 = wx1 * wy1 * ((vx1 && vy1) ? 1.f : 0.f);
    }

    // wave-uniform bitmask of valid points
    unsigned long long bal = __ballot(m);
    const float cnt = fmaxf((float)__popcll(bal), 1.f);

    float ax = 0.f, ay = 0.f;
    const float* fbase = feat + 2 * lane;   // lane owns channels {2*lane, 2*lane+1}

    while (bal) {
        const int e = (int)__builtin_ctzll(bal);   // uniform (scalar)
        bal &= bal - 1;
        const int   j0 = __shfl(i0, e), j1 = __shfl(i1, e);
        const int   j2 = __shfl(i2, e), j3 = __shfl(i3, e);
        const float v0 = __shfl(w0, e), v1 = __shfl(w1, e);
        const float v2 = __shfl(w2, e), v3 = __shfl(w3, e);

        const float2 f0 = *(const float2*)(fbase + j0);
        const float2 f1 = *(const float2*)(fbase + j1);
        const float2 f2 = *(const float2*)(fbase + j2);
        const float2 f3 = *(const float2*)(fbase + j3);

        ax += v0 * f0.x; ay += v0 * f0.y;
        ax += v1 * f1.x; ay += v1 * f1.y;
        ax += v2 * f2.x; ay += v2 * f2.y;
        ax += v3 * f3.x; ay += v3 * f3.y;
    }

    const float inv = 1.f / cnt;
    float2 o; o.x = ax * inv; o.y = ay * inv;
    *(float2*)(out + q * CC + 2 * lane) = o;
}

extern "C" void kernel_launch(void* const* d_in, const int* in_sizes, int n_in,
                              void* d_out, int out_size, void* d_ws, size_t ws_size,
                              hipStream_t stream) {
    const float* feat = (const float*)d_in[0];
    const float* I_   = (const float*)d_in[1];
    const float* E_   = (const float*)d_in[2];
    const float* grid = (const float*)d_in[3];
    float* out        = (float*)d_out;

    bev_sample_kernel<<<(BEV_H * BEV_W) / WPB, WPB * 64, 0, stream>>>(feat, I_, E_, grid, out);
}

// Round 3
// 22.244 us; speedup vs baseline: 1.3558x; 1.2333x over previous
//
#include <hip/hip_runtime.h>

#define BEV_H 150
#define BEV_W 150
#define DD    4
#define NCAM  6
#define CC    128
#define FH    48
#define FW    88
#define IMG_H 480.0f
#define IMG_W 800.0f

#define NPTS (NCAM * DD)   // 24 projected points per BEV cell
#define WPB  4             // waves (= BEV cells) per block, 2x2 patch

__global__ __launch_bounds__(WPB * 64) void bev_sample_kernel(
    const float* __restrict__ feat,   // (NCAM, FH, FW, C)
    const float* __restrict__ I_,     // (NCAM, 3, 3)
    const float* __restrict__ E_,     // (NCAM, 4, 4)
    const float* __restrict__ grid,   // (D, 3, BEV_H, BEV_W)
    float* __restrict__ out)          // (Q, C)
{
    const int lane = threadIdx.x & 63;
    const int wv   = threadIdx.x >> 6;

    // bijective XCD-chunked swizzle: nwg=5625, q8=703, r8=1
    int p;
    {
        const int b   = blockIdx.x;
        const int xcd = b & 7;
        const int ii  = b >> 3;
        p = (xcd == 0) ? ii : (704 + (xcd - 1) * 703 + ii);
    }
    const int ph = p / 75;          // patch row (2 BEV rows per patch)
    const int pw = p - ph * 75;
    const int h  = ph * 2 + (wv >> 1);
    const int w  = pw * 2 + (wv & 1);
    const int q  = h * BEV_W + w;

    // per-point state (lanes 0..23 own one (cam,depth) point each)
    int   iT = 0, iB = 0;                       // element offsets of (cy0,b) / (cy1,b) rows
    float wTL = 0.f, wTR = 0.f, wBL = 0.f, wBR = 0.f;
    bool  m = false;

    if (lane < NPTS) {
        const int n = lane >> 2;   // camera
        const int d = lane & 3;    // depth

        // l2i = I[n] @ E[n][:3,:]
        float M[12];
        #pragma unroll
        for (int i = 0; i < 3; ++i) {
            #pragma unroll
            for (int j = 0; j < 4; ++j) {
                float acc = 0.f;
                #pragma unroll
                for (int k = 0; k < 3; ++k)
                    acc += I_[n * 9 + i * 3 + k] * E_[n * 16 + k * 4 + j];
                M[i * 4 + j] = acc;
            }
        }

        const float gx = grid[((d * 3 + 0) * BEV_H + h) * BEV_W + w];
        const float gy = grid[((d * 3 + 1) * BEV_H + h) * BEV_W + w];
        const float gz = grid[((d * 3 + 2) * BEV_H + h) * BEV_W + w];
        const float x = gx * 102.4f - 51.2f;
        const float y = gy * 102.4f - 51.2f;
        const float z = gz * 8.0f   - 5.0f;

        const float p0 = M[0] * x + M[1] * y + M[2]  * z + M[3];
        const float p1 = M[4] * x + M[5] * y + M[6]  * z + M[7];
        const float p2 = M[8] * x + M[9] * y + M[10] * z + M[11];

        const float eps = 1e-5f;
        const float zc = fmaxf(p2, eps);
        const float u = (p0 / zc) * (1.0f / IMG_W);
        const float v = (p1 / zc) * (1.0f / IMG_H);
        m = (p2 > eps) && (u > 0.f) && (u < 1.f) && (v > 0.f) && (v < 1.f);

        const float px = u * (float)FW - 0.5f;
        const float py = v * (float)FH - 0.5f;
        const float fx0 = floorf(px), fy0 = floorf(py);
        const int x0 = (int)fx0, y0 = (int)fy0;
        const int x1 = x0 + 1,   y1 = y0 + 1;
        const float wx1 = px - fx0, wy1 = py - fy0;
        const float wx0 = 1.f - wx1, wy0 = 1.f - wy1;

        const bool vx0 = (x0 >= 0) && (x0 < FW);
        const bool vx1 = (x1 >= 0) && (x1 < FW);
        const bool vy0 = (y0 >= 0) && (y0 < FH);
        const bool vy1 = (y1 >= 0) && (y1 < FH);
        const int cx0 = min(max(x0, 0), FW - 1), cx1 = min(max(x1, 0), FW - 1);
        const int cy0 = min(max(y0, 0), FH - 1), cy1 = min(max(y1, 0), FH - 1);

        const float w0v = wx0 * wy0 * ((vx0 && vy0) ? 1.f : 0.f);  // (x0,y0)
        const float w1v = wx1 * wy0 * ((vx1 && vy0) ? 1.f : 0.f);  // (x1,y0)
        const float w2v = wx0 * wy1 * ((vx0 && vy1) ? 1.f : 0.f);  // (x0,y1)
        const float w3v = wx1 * wy1 * ((vx1 && vy1) ? 1.f : 0.f);  // (x1,y1)

        // base column for the paired-column (1 KB) load; remap weights onto
        // columns {b, b+1} (handles all clamp edge cases via zero weights)
        const int bx = min(max(x0, 0), FW - 2);
        wTL = ((cx0 == bx)     ? w0v : 0.f) + ((cx1 == bx)     ? w1v : 0.f);
        wTR = ((cx0 == bx + 1) ? w0v : 0.f) + ((cx1 == bx + 1) ? w1v : 0.f);
        wBL = ((cx0 == bx)     ? w2v : 0.f) + ((cx1 == bx)     ? w3v : 0.f);
        wBR = ((cx0 == bx + 1) ? w2v : 0.f) + ((cx1 == bx + 1) ? w3v : 0.f);

        const int base = n * FH * FW;
        iT = (base + cy0 * FW + bx) * CC;
        iB = (base + cy1 * FW + bx) * CC;
    }

    unsigned long long bal = __ballot(m) & 0xFFFFFFull;
    const float cnt = fmaxf((float)__popcll(bal), 1.f);

    float ax = 0.f, ay = 0.f, az = 0.f, aw = 0.f;
    const int loff = 4 * lane;       // lanes 0-31: col b ch 4l..; 32-63: col b+1
    const bool lowhalf = (lane < 32);

    while (bal) {
        const int e0 = (int)__builtin_ctzll(bal);
        bal &= bal - 1;
        const bool has2 = (bal != 0);
        const unsigned long long b2 = has2 ? bal : 1ull;
        const int e1 = (int)__builtin_ctzll(b2);
        const float s = has2 ? 1.f : 0.f;
        bal &= bal - 1;   // safe when bal==0

        const int jT0 = __builtin_amdgcn_readlane(iT, e0);
        const int jB0 = __builtin_amdgcn_readlane(iB, e0);
        const int jT1 = __builtin_amdgcn_readlane(iT, e1);
        const int jB1 = __builtin_amdgcn_readlane(iB, e1);

        const float tL0 = __uint_as_float(__builtin_amdgcn_readlane(__float_as_uint(wTL), e0));
        const float tR0 = __uint_as_float(__builtin_amdgcn_readlane(__float_as_uint(wTR), e0));
        const float bL0 = __uint_as_float(__builtin_amdgcn_readlane(__float_as_uint(wBL), e0));
        const float bR0 = __uint_as_float(__builtin_amdgcn_readlane(__float_as_uint(wBR), e0));
        const float tL1 = __uint_as_float(__builtin_amdgcn_readlane(__float_as_uint(wTL), e1));
        const float tR1 = __uint_as_float(__builtin_amdgcn_readlane(__float_as_uint(wTR), e1));
        const float bL1 = __uint_as_float(__builtin_amdgcn_readlane(__float_as_uint(wBL), e1));
        const float bR1 = __uint_as_float(__builtin_amdgcn_readlane(__float_as_uint(wBR), e1));

        const float wT0 = lowhalf ? tL0 : tR0;
        const float wB0 = lowhalf ? bL0 : bR0;
        const float wT1 = s * (lowhalf ? tL1 : tR1);
        const float wB1 = s * (lowhalf ? bL1 : bR1);

        const float4 fT0 = *(const float4*)(feat + jT0 + loff);
        const float4 fB0 = *(const float4*)(feat + jB0 + loff);
        const float4 fT1 = *(const float4*)(feat + jT1 + loff);
        const float4 fB1 = *(const float4*)(feat + jB1 + loff);

        ax += wT0 * fT0.x + wB0 * fB0.x + wT1 * fT1.x + wB1 * fB1.x;
        ay += wT0 * fT0.y + wB0 * fB0.y + wT1 * fT1.y + wB1 * fB1.y;
        az += wT0 * fT0.z + wB0 * fB0.z + wT1 * fT1.z + wB1 * fB1.z;
        aw += wT0 * fT0.w + wB0 * fB0.w + wT1 * fT1.w + wB1 * fB1.w;
    }

    // combine column-halves: lane l (<32) + lane l+32 hold the two column
    // contributions of channels 4l..4l+3
    ax += __shfl_xor(ax, 32);
    ay += __shfl_xor(ay, 32);
    az += __shfl_xor(az, 32);
    aw += __shfl_xor(aw, 32);

    if (lane < 32) {
        const float inv = 1.f / cnt;
        float4 o;
        o.x = ax * inv; o.y = ay * inv; o.z = az * inv; o.w = aw * inv;
        *(float4*)(out + q * CC + 4 * lane) = o;
    }
}

extern "C" void kernel_launch(void* const* d_in, const int* in_sizes, int n_in,
                              void* d_out, int out_size, void* d_ws, size_t ws_size,
                              hipStream_t stream) {
    const float* feat = (const float*)d_in[0];
    const float* I_   = (const float*)d_in[1];
    const float* E_   = (const float*)d_in[2];
    const float* grid = (const float*)d_in[3];
    float* out        = (float*)d_out;

    bev_sample_kernel<<<(BEV_H * BEV_W) / WPB, WPB * 64, 0, stream>>>(feat, I_, E_, grid, out);
}

// Round 4
// 19.843 us; speedup vs baseline: 1.5198x; 1.1210x over previous
//
#include <hip/hip_runtime.h>

#define BEV_H 150
#define BEV_W 150
#define DD    4
#define NCAM  6
#define CC    128
#define FH    48
#define FW    88
#define IMG_Hf 480.0f
#define IMG_Wf 800.0f
#define NPTS  24

__device__ __forceinline__ float rdlanef(float x, int l) {
    return __uint_as_float((unsigned)__builtin_amdgcn_readlane((int)__float_as_uint(x), l));
}

__global__ __launch_bounds__(128) void bev_sample_kernel(
    const float* __restrict__ feat,   // (NCAM, FH, FW, C)
    const float* __restrict__ I_,     // (NCAM, 3, 3)
    const float* __restrict__ E_,     // (NCAM, 4, 4)
    const float* __restrict__ grid,   // (D, 3, BEV_H, BEV_W)
    float* __restrict__ out)          // (Q, C)
{
    const int tid  = threadIdx.x;
    const int lane = tid & 63;
    const int wv   = tid >> 6;          // 2 waves per block
    const int l32  = lane & 31;
    const bool lowhalf = (lane < 32);

    // --- cooperative l2i = I @ E[:3,:] in LDS (6 cams x 12) ---
    __shared__ float s_l2i[NCAM][12];
    if (tid < NCAM * 12) {
        const int n = tid / 12, r = tid % 12;
        const int i = r >> 2, j = r & 3;
        float acc = 0.f;
        #pragma unroll
        for (int k = 0; k < 3; ++k)
            acc += I_[n * 9 + i * 3 + k] * E_[n * 16 + k * 4 + j];
        s_l2i[n][r] = acc;
    }
    __syncthreads();

    // --- bijective XCD-chunked swizzle: nwg=5625, 704 + 7*703 ---
    int p;
    {
        const int b = blockIdx.x;
        const int xcd = b & 7, ii = b >> 3;
        p = (xcd == 0) ? ii : (704 + (xcd - 1) * 703 + ii);
    }
    const int ph = p / 75, pw = p - ph * 75;   // 75x75 patches of 2x2 cells
    const int h  = ph * 2 + wv;
    const int wA = pw * 2;                     // wave handles cells (h,wA),(h,wA+1)
    const int qA = h * BEV_W + wA;

    // --- per-point projection: lanes 0-23 = cell A, lanes 32-55 = cell B ---
    int   iT = 0, iB = 0;
    float wTL = 0.f, wTR = 0.f, wBL = 0.f, wBR = 0.f;
    bool  m = false;

    const bool actA = (lane < NPTS);
    const bool actB = (lane >= 32) && (lane < 32 + NPTS);
    if (actA || actB) {
        const int n = l32 >> 2;      // camera
        const int d = l32 & 3;       // depth
        const int wc = wA + (actB ? 1 : 0);

        const float gx = grid[((d * 3 + 0) * BEV_H + h) * BEV_W + wc];
        const float gy = grid[((d * 3 + 1) * BEV_H + h) * BEV_W + wc];
        const float gz = grid[((d * 3 + 2) * BEV_H + h) * BEV_W + wc];
        const float x = gx * 102.4f - 51.2f;
        const float y = gy * 102.4f - 51.2f;
        const float z = gz * 8.0f   - 5.0f;

        const float4 M0 = *(const float4*)&s_l2i[n][0];
        const float4 M1 = *(const float4*)&s_l2i[n][4];
        const float4 M2 = *(const float4*)&s_l2i[n][8];
        const float p0 = M0.x * x + M0.y * y + M0.z * z + M0.w;
        const float p1 = M1.x * x + M1.y * y + M1.z * z + M1.w;
        const float p2 = M2.x * x + M2.y * y + M2.z * z + M2.w;

        const float eps = 1e-5f;
        const float zc = fmaxf(p2, eps);
        const float u = (p0 / zc) * (1.0f / IMG_Wf);   // exact div to match ref masks
        const float v = (p1 / zc) * (1.0f / IMG_Hf);
        m = (p2 > eps) && (u > 0.f) && (u < 1.f) && (v > 0.f) && (v < 1.f);

        const float px = u * (float)FW - 0.5f;
        const float py = v * (float)FH - 0.5f;
        const float fx0 = floorf(px), fy0 = floorf(py);
        const int x0 = (int)fx0, y0 = (int)fy0;
        const int x1 = x0 + 1,   y1 = y0 + 1;
        const float wx1 = px - fx0, wy1 = py - fy0;
        const float wx0 = 1.f - wx1, wy0 = 1.f - wy1;

        const bool vx0 = (x0 >= 0) && (x0 < FW);
        const bool vx1 = (x1 >= 0) && (x1 < FW);
        const bool vy0 = (y0 >= 0) && (y0 < FH);
        const bool vy1 = (y1 >= 0) && (y1 < FH);
        const int cx0 = min(max(x0, 0), FW - 1), cx1 = min(max(x1, 0), FW - 1);
        const int cy0 = min(max(y0, 0), FH - 1), cy1 = min(max(y1, 0), FH - 1);

        const float w0v = wx0 * wy0 * ((vx0 && vy0) ? 1.f : 0.f);
        const float w1v = wx1 * wy0 * ((vx1 && vy0) ? 1.f : 0.f);
        const float w2v = wx0 * wy1 * ((vx0 && vy1) ? 1.f : 0.f);
        const float w3v = wx1 * wy1 * ((vx1 && vy1) ? 1.f : 0.f);

        // paired-column remap onto {bx, bx+1}
        const int bx = min(max(x0, 0), FW - 2);
        wTL = ((cx0 == bx)     ? w0v : 0.f) + ((cx1 == bx)     ? w1v : 0.f);
        wTR = ((cx0 == bx + 1) ? w0v : 0.f) + ((cx1 == bx + 1) ? w1v : 0.f);
        wBL = ((cx0 == bx)     ? w2v : 0.f) + ((cx1 == bx)     ? w3v : 0.f);
        wBR = ((cx0 == bx + 1) ? w2v : 0.f) + ((cx1 == bx + 1) ? w3v : 0.f);

        const int base = n * FH * FW;
        iT = (base + cy0 * FW + bx) * CC;
        iB = (base + cy1 * FW + bx) * CC;
    }

    const unsigned long long bal = __ballot(m);
    unsigned long long balA = bal & 0xFFFFFFull;
    unsigned long long balB = (bal >> 32) & 0xFFFFFFull;
    const float cntA = fmaxf((float)__popcll(balA), 1.f);
    const float cntB = fmaxf((float)__popcll(balB), 1.f);

    float aAx = 0.f, aAy = 0.f, aAz = 0.f, aAw = 0.f;
    float aBx = 0.f, aBy = 0.f, aBz = 0.f, aBw = 0.f;
    const int loff = 4 * lane;   // lanes 0-31: col b; 32-63: col b+1

    while (balA | balB) {
        // extract up to 2 entries per cell; dummies repeat a safe lane (L1 hit, s=0)
        int eA0 = 0, eA1 = 0, eB0 = 32, eB1 = 32;
        float sA0 = 0.f, sA1 = 0.f, sB0 = 0.f, sB1 = 0.f;
        if (balA) {
            eA0 = (int)__builtin_ctzll(balA); balA &= balA - 1; sA0 = 1.f;
            if (balA) { eA1 = (int)__builtin_ctzll(balA); balA &= balA - 1; sA1 = 1.f; }
            else eA1 = eA0;
        }
        if (balB) {
            eB0 = 32 + (int)__builtin_ctzll(balB); balB &= balB - 1; sB0 = 1.f;
            if (balB) { eB1 = 32 + (int)__builtin_ctzll(balB); balB &= balB - 1; sB1 = 1.f; }
            else eB1 = eB0;
        }

        const int jTA0 = __builtin_amdgcn_readlane(iT, eA0), jBA0 = __builtin_amdgcn_readlane(iB, eA0);
        const int jTA1 = __builtin_amdgcn_readlane(iT, eA1), jBA1 = __builtin_amdgcn_readlane(iB, eA1);
        const int jTB0 = __builtin_amdgcn_readlane(iT, eB0), jBB0 = __builtin_amdgcn_readlane(iB, eB0);
        const int jTB1 = __builtin_amdgcn_readlane(iT, eB1), jBB1 = __builtin_amdgcn_readlane(iB, eB1);

        const float4 fTA0 = *(const float4*)(feat + jTA0 + loff);
        const float4 fBA0 = *(const float4*)(feat + jBA0 + loff);
        const float4 fTA1 = *(const float4*)(feat + jTA1 + loff);
        const float4 fBA1 = *(const float4*)(feat + jBA1 + loff);
        const float4 fTB0 = *(const float4*)(feat + jTB0 + loff);
        const float4 fBB0 = *(const float4*)(feat + jBB0 + loff);
        const float4 fTB1 = *(const float4*)(feat + jTB1 + loff);
        const float4 fBB1 = *(const float4*)(feat + jBB1 + loff);

        const float wTA0 = sA0 * (lowhalf ? rdlanef(wTL, eA0) : rdlanef(wTR, eA0));
        const float wBA0 = sA0 * (lowhalf ? rdlanef(wBL, eA0) : rdlanef(wBR, eA0));
        const float wTA1 = sA1 * (lowhalf ? rdlanef(wTL, eA1) : rdlanef(wTR, eA1));
        const float wBA1 = sA1 * (lowhalf ? rdlanef(wBL, eA1) : rdlanef(wBR, eA1));
        const float wTB0 = sB0 * (lowhalf ? rdlanef(wTL, eB0) : rdlanef(wTR, eB0));
        const float wBB0 = sB0 * (lowhalf ? rdlanef(wBL, eB0) : rdlanef(wBR, eB0));
        const float wTB1 = sB1 * (lowhalf ? rdlanef(wTL, eB1) : rdlanef(wTR, eB1));
        const float wBB1 = sB1 * (lowhalf ? rdlanef(wBL, eB1) : rdlanef(wBR, eB1));

        aAx += wTA0 * fTA0.x + wBA0 * fBA0.x + wTA1 * fTA1.x + wBA1 * fBA1.x;
        aAy += wTA0 * fTA0.y + wBA0 * fBA0.y + wTA1 * fTA1.y + wBA1 * fBA1.y;
        aAz += wTA0 * fTA0.z + wBA0 * fBA0.z + wTA1 * fTA1.z + wBA1 * fBA1.z;
        aAw += wTA0 * fTA0.w + wBA0 * fBA0.w + wTA1 * fTA1.w + wBA1 * fBA1.w;
        aBx += wTB0 * fTB0.x + wBB0 * fBB0.x + wTB1 * fTB1.x + wBB1 * fBB1.x;
        aBy += wTB0 * fTB0.y + wBB0 * fBB0.y + wTB1 * fTB1.y + wBB1 * fBB1.y;
        aBz += wTB0 * fTB0.z + wBB0 * fBB0.z + wTB1 * fTB1.z + wBB1 * fBB1.z;
        aBw += wTB0 * fTB0.w + wBB0 * fBB0.w + wTB1 * fTB1.w + wBB1 * fBB1.w;
    }

    // combine column halves (lane l <-> l+32 hold the two column contributions)
    aAx += __shfl_xor(aAx, 32);  aAy += __shfl_xor(aAy, 32);
    aAz += __shfl_xor(aAz, 32);  aAw += __shfl_xor(aAw, 32);
    aBx += __shfl_xor(aBx, 32);  aBy += __shfl_xor(aBy, 32);
    aBz += __shfl_xor(aBz, 32);  aBw += __shfl_xor(aBw, 32);

    // lanes 0-31 store cell A, lanes 32-63 store cell B
    const float inv = lowhalf ? (1.f / cntA) : (1.f / cntB);
    const int   q   = lowhalf ? qA : (qA + 1);
    float4 o;
    o.x = (lowhalf ? aAx : aBx) * inv;
    o.y = (lowhalf ? aAy : aBy) * inv;
    o.z = (lowhalf ? aAz : aBz) * inv;
    o.w = (lowhalf ? aAw : aBw) * inv;
    *(float4*)(out + q * CC + 4 * l32) = o;
}

extern "C" void kernel_launch(void* const* d_in, const int* in_sizes, int n_in,
                              void* d_out, int out_size, void* d_ws, size_t ws_size,
                              hipStream_t stream) {
    const float* feat = (const float*)d_in[0];
    const float* I_   = (const float*)d_in[1];
    const float* E_   = (const float*)d_in[2];
    const float* grid = (const float*)d_in[3];
    float* out        = (float*)d_out;

    bev_sample_kernel<<<(BEV_H / 2) * (BEV_W / 2), 128, 0, stream>>>(feat, I_, E_, grid, out);
}